// Round 13
// baseline (178.093 us; speedup 1.0000x reference)
//
#include <hip/hip_runtime.h>
#include <hip/hip_cooperative_groups.h>

namespace cg = cooperative_groups;

#define DEVI static __device__ __forceinline__

typedef __attribute__((ext_vector_type(8))) short s8v;    // 8 bf16 (4 VGPR)
typedef __attribute__((ext_vector_type(4))) float f32x4;
typedef unsigned short us_t;
typedef unsigned int u32;

constexpr int NT_ = 256;
constexpr int B_ = 256, HW_ = 1024, IN_ = 512, HID_ = 1024, H3_ = 3072;
constexpr int XD_ = 1537;
constexpr int FLAT_ = 16384;

// ---- workspace layout (float offsets); ws_size = 256 MiB ----
constexpr int OFF_WIHFBF = 0;                 // 3072*512 bf16
constexpr int OFF_WIHM2  = 393216;            // 3072*2048 bf16 (hi|lo)
constexpr int OFF_WIHC   = 5111808;           // 3072 f32
constexpr int OFF_CNTD   = 5114880;           // 256
constexpr int OFF_FLAGS  = 5115136;           // 128 ints
constexpr int OFF_FEATBF = 5115264;           // 256*512 bf16
constexpr int OFF_GI     = 5180800;           // 786432 f32
constexpr int OFF_GH     = 5967232;           // 786432
constexpr int OFF_H0     = 6753664;           // 262144
constexpr int OFF_H1     = 7015808;           // 262144
constexpr int OFF_WSIG   = 7277952;           // 262144 f32 (tail path)
constexpr int OFF_HHI    = 7540096;           // 256*1024 bf16
constexpr int OFF_WSIG2  = 7671168;           // 256*2048 bf16 (hi|lo)
constexpr int OFF_C2BF   = 7933312;           // 256*16384 bf16 (dead after lin)
// aliases / extras:
constexpr int OFF_PART = OFF_GI;              // lin split-K partials (16*131072)
constexpr int OFF_PW   = OFF_C2BF;            // stepW partials 8*262144 (dead c2bf)
constexpr int OFF_PA2  = 14224768;            // stepA partials 6*786432 f32

struct Params {
  const float* grid;
  const float* c1w; const float* c1b;
  const float* c2w; const float* c2b;
  const float* linw; const float* linb;
  const float* wih; const float* whh;
  const float* bih; const float* bhh;
  const float* ww;  const float* wb;
  const float* incw; const float* incb;
  const float* termw; const float* termb;
  const int* max_steps;
  float* out;   // [0:256) count, [256:262400) mask [256][1024]
  float* ws;
};

DEVI float sigm(float x) { return 1.f / (1.f + __expf(-x)); }
DEVI float tanh_(float x) { return 1.f - 2.f / (__expf(2.f * x) + 1.f); }
DEVI float2 ld2(const float* p) { return *(const float2*)p; }
DEVI void ld4(float* d, const float* p) {
  float4 v = *(const float4*)p; d[0] = v.x; d[1] = v.y; d[2] = v.z; d[3] = v.w;
}
DEVI us_t f2bf(float x) {            // RNE f32->bf16
  union { float f; u32 u; } v; v.f = x;
  u32 r = v.u + 0x7FFFu + ((v.u >> 16) & 1u);
  return (us_t)(r >> 16);
}
DEVI float bf2f(us_t h) {
  union { u32 u; float f; } v; v.u = ((u32)h) << 16; return v.f;
}
DEVI u32 pack2(float a, float b) { return (u32)f2bf(a) | ((u32)f2bf(b) << 16); }

// ---- staging loaders: 8 contiguous elements -> 8 bf16 (16B-aligned sources) ----
DEVI s8v ld8w(const us_t* p) { return *(const s8v*)p; }
DEVI s8v ld8w(const float* p) {      // f32 source, cvt in-register (RNE, bit-identical)
  float4 v0 = *(const float4*)p;
  float4 v1 = *(const float4*)(p + 4);
  union { u32 u[4]; s8v s; } r;
  r.u[0] = pack2(v0.x, v0.y); r.u[1] = pack2(v0.z, v0.w);
  r.u[2] = pack2(v1.x, v1.y); r.u[3] = pack2(v1.z, v1.w);
  return r.s;
}

// ---------------- conv: 2 blocks per image, 22.3 KB LDS (R11-proven) ----------------
__global__ __launch_bounds__(NT_) void conv_kernel(Params p) {
  __shared__ float s_in[20 * 34];
  __shared__ float s_c1[8 * 18 * 34];
  const int tid = threadIdx.x;
  const int b = blockIdx.x >> 1;
  const int r0 = (blockIdx.x & 1) * 16;
  for (int i = tid; i < 20 * 34; i += NT_) s_in[i] = 0.f;
  for (int i = tid; i < 8 * 18 * 34; i += NT_) s_c1[i] = 0.f;
  __syncthreads();
  for (int i = tid; i < 20 * 32; i += NT_) {
    const int ry = i >> 5, x = i & 31;
    const int iy = r0 - 2 + ry;
    if (iy >= 0 && iy < 32)
      s_in[ry * 34 + x + 1] = p.grid[b * 1024 + iy * 32 + x];
  }
  __syncthreads();
  if (tid < 144) {
    const int cy = tid >> 3;
    const int xg = (tid & 7) * 4;
    const int cr = r0 - 1 + cy;
    if (cr >= 0 && cr < 32) {
      float win[3][6];
      #pragma unroll
      for (int dy = 0; dy < 3; ++dy)
        #pragma unroll
        for (int c = 0; c < 6; ++c) win[dy][c] = s_in[(cy + dy) * 34 + xg + c];
      float acc[8][4];
      #pragma unroll
      for (int oc = 0; oc < 8; ++oc)
        #pragma unroll
        for (int i = 0; i < 4; ++i) acc[oc][i] = p.c1b[oc];
      #pragma unroll
      for (int oc = 0; oc < 8; ++oc)
        #pragma unroll
        for (int dy = 0; dy < 3; ++dy)
          #pragma unroll
          for (int dx = 0; dx < 3; ++dx) {
            const float w = p.c1w[oc * 9 + dy * 3 + dx];
            #pragma unroll
            for (int i = 0; i < 4; ++i)
              acc[oc][i] = fmaf(w, win[dy][i + dx], acc[oc][i]);
          }
      #pragma unroll
      for (int oc = 0; oc < 8; ++oc)
        #pragma unroll
        for (int i = 0; i < 4; ++i)
          s_c1[oc * 612 + cy * 34 + xg + i + 1] = fmaxf(acc[oc][i], 0.f);
    }
  }
  __syncthreads();
  {
    const int pos = tid * 2;
    const int y2 = pos >> 5, x2 = pos & 31;
    float acc[16][2];
    #pragma unroll
    for (int oc = 0; oc < 16; ++oc) { acc[oc][0] = p.c2b[oc]; acc[oc][1] = p.c2b[oc]; }
    for (int ic = 0; ic < 8; ++ic) {
      float win[3][4];
      #pragma unroll
      for (int dy = 0; dy < 3; ++dy)
        #pragma unroll
        for (int c = 0; c < 4; ++c)
          win[dy][c] = s_c1[ic * 612 + (y2 + dy) * 34 + x2 + c];
      #pragma unroll
      for (int oc = 0; oc < 16; ++oc)
        #pragma unroll
        for (int dy = 0; dy < 3; ++dy)
          #pragma unroll
          for (int dx = 0; dx < 3; ++dx) {
            const float w = p.c2w[oc * 72 + ic * 9 + dy * 3 + dx];
            acc[oc][0] = fmaf(w, win[dy][dx + 0], acc[oc][0]);
            acc[oc][1] = fmaf(w, win[dy][dx + 1], acc[oc][1]);
          }
    }
    us_t* dst = (us_t*)(p.ws + OFF_C2BF) + b * FLAT_;
    #pragma unroll
    for (int oc = 0; oc < 16; ++oc)
      *(u32*)(dst + oc * 1024 + (r0 + y2) * 32 + x2) =
          pack2(fmaxf(acc[oc][0], 0.f), fmaxf(acc[oc][1], 0.f));
  }
}

// ---- prep: ONLY the wih repack (misaligned stride 1537) + flags; float4 loads ----
__global__ __launch_bounds__(NT_) void prep_kernel(Params p) {
  const int gt = blockIdx.x * NT_ + threadIdx.x;
  const int gs = 1024 * NT_;
  us_t* wihf = (us_t*)(p.ws + OFF_WIHFBF);
  us_t* wihm2 = (us_t*)(p.ws + OFF_WIHM2);
  float* wihc = p.ws + OFF_WIHC;
  int* flags = (int*)(p.ws + OFF_FLAGS);
  for (int i4 = gt; i4 < (H3_ * XD_) / 4; i4 += gs) {   // 1,180,416 units exact
    float4 v = *(const float4*)(p.wih + (size_t)i4 * 4);
    const float vv[4] = {v.x, v.y, v.z, v.w};
    #pragma unroll
    for (int e = 0; e < 4; ++e) {
      const int i = i4 * 4 + e;
      const int n = i / XD_;               // magic-mul
      const int k = i - n * XD_;
      const float x = vv[e];
      if (k < 512) {
        wihf[n * 512 + k] = f2bf(x);
      } else if (k < 1536) {
        const int kk = k - 512;
        const us_t hi = f2bf(x);
        wihm2[(size_t)n * 2048 + kk] = hi;
        wihm2[(size_t)n * 2048 + 1024 + kk] = f2bf(x - bf2f(hi));
      } else {
        wihc[n] = x;
      }
    }
  }
  if (gt < 128) flags[gt] = 1;
}

// ---- MFMA block: C[64][128] = sum_k A[m][k]*B[n][k]; B bf16 or f32(stage-cvt) ----
// 256 threads = 4 waves; wave w owns 64x32; K = nc*64.
// LDS swizzle: 16B unit (r,u) -> slot r*8 + (u ^ (r&7)).
template <typename TB>
DEVI void mfma_block(const us_t* __restrict__ Ag, int lda,
                     const TB* __restrict__ Bg, int ldb, int nc,
                     us_t* __restrict__ sA, us_t* __restrict__ sB,
                     float* __restrict__ dst, int ldd) {
  const int tid = threadIdx.x;
  const int ar = tid >> 3, au = tid & 7;
  const int sw = au ^ (ar & 7);
  const int abase = (ar * 8 + sw) * 8;
  const us_t* a0p = Ag + (size_t)ar * lda + au * 8;
  const us_t* a1p = Ag + (size_t)(ar + 32) * lda + au * 8;
  const TB* b0p = Bg + (size_t)ar * ldb + au * 8;
  const TB* b1p = Bg + (size_t)(ar + 32) * ldb + au * 8;
  const TB* b2p = Bg + (size_t)(ar + 64) * ldb + au * 8;
  const TB* b3p = Bg + (size_t)(ar + 96) * ldb + au * 8;
  f32x4 acc[4][2];
  #pragma unroll
  for (int f = 0; f < 4; ++f) { acc[f][0] = (f32x4)0.f; acc[f][1] = (f32x4)0.f; }
  s8v ra0 = ld8w(a0p);
  s8v ra1 = ld8w(a1p);
  s8v rb0 = ld8w(b0p);
  s8v rb1 = ld8w(b1p);
  s8v rb2 = ld8w(b2p);
  s8v rb3 = ld8w(b3p);
  const int w = tid >> 6;
  const int lane = tid & 63;
  const int l15 = lane & 15, l4 = lane >> 4;
  const int rsw = l15 & 7;
  int c = 0;
  for (;;) {
    __syncthreads();
    *(s8v*)(sA + abase) = ra0;
    *(s8v*)(sA + abase + 2048) = ra1;
    *(s8v*)(sB + abase) = rb0;
    *(s8v*)(sB + abase + 2048) = rb1;
    *(s8v*)(sB + abase + 4096) = rb2;
    *(s8v*)(sB + abase + 6144) = rb3;
    ++c;
    if (c < nc) {
      const int ko = c * 64;
      ra0 = ld8w(a0p + ko);
      ra1 = ld8w(a1p + ko);
      rb0 = ld8w(b0p + ko);
      rb1 = ld8w(b1p + ko);
      rb2 = ld8w(b2p + ko);
      rb3 = ld8w(b3p + ko);
    }
    __syncthreads();
    #pragma unroll
    for (int kk = 0; kk < 2; ++kk) {
      const int uoff = ((kk * 4 + l4) ^ rsw) * 8;
      s8v bA = *(const s8v*)(sB + (w * 32 + l15) * 64 + uoff);
      s8v bB = *(const s8v*)(sB + (w * 32 + 16 + l15) * 64 + uoff);
      #pragma unroll
      for (int f = 0; f < 4; ++f) {
        s8v a = *(const s8v*)(sA + (f * 16 + l15) * 64 + uoff);
        acc[f][0] = __builtin_amdgcn_mfma_f32_16x16x32_bf16(a, bA, acc[f][0], 0, 0, 0);
        acc[f][1] = __builtin_amdgcn_mfma_f32_16x16x32_bf16(a, bB, acc[f][1], 0, 0, 0);
      }
    }
    if (c >= nc) break;
  }
  #pragma unroll
  for (int f = 0; f < 4; ++f)
    #pragma unroll
    for (int g = 0; g < 2; ++g) {
      float* dp = dst + (size_t)(f * 16 + l4 * 4) * ldd + w * 32 + g * 16 + l15;
      #pragma unroll
      for (int j = 0; j < 4; ++j) dp[(size_t)j * ldd] = acc[f][g][j];
    }
}

// ------ linear: part[ks] = c2f_bf @ linw(f32, stage-cvt)^T ------
__global__ __launch_bounds__(NT_) void lin_mfma(Params p) {
  __shared__ us_t sm[12288];
  const int b = blockIdx.x;                // 256 = 16ks x 4mt x 4nt
  const int ks = b & 15, t = b >> 4;
  const int mt = t >> 2, nt = t & 3;
  const us_t* A = (us_t*)(p.ws + OFF_C2BF) + (size_t)mt * 64 * FLAT_ + ks * 1024;
  const float* B = p.linw + (size_t)nt * 128 * FLAT_ + ks * 1024;
  float* dst = p.ws + OFF_PART + ks * (B_ * IN_) + mt * 64 * IN_ + nt * 128;
  mfma_block(A, FLAT_, B, FLAT_, 16, sm, sm + 4096, dst, IN_);
}

// ---------------- red: reduce split-K -> feat bf16 ----------------
__global__ __launch_bounds__(NT_) void red_kernel(Params p) {
  const int gt = blockIdx.x * NT_ + threadIdx.x;   // 512 blocks exact
  const int o = gt & (IN_ - 1);
  const float* part = p.ws + OFF_PART;
  float s = p.linb[o];
  #pragma unroll
  for (int ks = 0; ks < 16; ++ks) s += part[ks * (B_ * IN_) + gt];
  ((us_t*)(p.ws + OFF_FEATBF))[gt] = f2bf(s);
}

// ---------------- gi_base = feat @ wihf^T ----------------
__global__ __launch_bounds__(NT_) void a1_mfma(Params p) {
  __shared__ us_t sm[12288];
  const int b = blockIdx.x;                // 96 = 4mt*24nt
  const int mt = b / 24, nt = b - mt * 24;
  const us_t* A = (us_t*)(p.ws + OFF_FEATBF) + (size_t)mt * 64 * IN_;
  const us_t* B = (us_t*)(p.ws + OFF_WIHFBF) + (size_t)nt * 128 * IN_;
  float* dst = p.ws + OFF_GI + (size_t)mt * 64 * H3_ + nt * 128;
  mfma_block(A, IN_, B, IN_, 8, sm, sm + 4096, dst, H3_);
}

// ------- stepA: G1 only, split-K=2: 576 = 3 terms x 2ks x 96 tiles -------
__global__ __launch_bounds__(NT_) void stepA_mfma(Params p, int step) {
  if (((volatile int*)(p.ws + OFF_FLAGS))[step - 1]) return;
  __shared__ us_t sm[12288];
  const int b = blockIdx.x;
  const int term = b / 192;
  const int r = b - term * 192;
  const int ks = r / 96;
  const int t = r - ks * 96;
  const int mt = t / 24, nt = t - mt * 24;
  const us_t* A = (us_t*)(p.ws + OFF_WSIG2) + (size_t)mt * 64 * 2048 +
                  (term == 1 ? 1024 : 0) + ks * 512;
  const us_t* B = (us_t*)(p.ws + OFF_WIHM2) + (size_t)nt * 128 * 2048 +
                  (term == 2 ? 1024 : 0) + ks * 512;
  float* dst = p.ws + OFF_PA2 + (size_t)(term * 2 + ks) * 786432 +
               (size_t)mt * 64 * H3_ + nt * 128;
  mfma_block(A, 2048, B, 2048, 8, sm, sm + 4096, dst, H3_);
}

// ---- stepG: fold 6 G1-partials + gh + cntd*wihc, gates once/row, dots, flag ----
__global__ __launch_bounds__(NT_) void stepG_kernel(Params p, int step) {
  int* flags = (int*)(p.ws + OFF_FLAGS);
  if (step > 0 && ((volatile int*)flags)[step - 1]) return;
  __shared__ float sred[8];
  const int row = blockIdx.x;
  const int tid = threadIdx.x;
  const size_t base = (size_t)row * H3_;
  float* const gi = p.ws + OFF_GI + base;
  const float* const gh = p.ws + OFF_GH + base;
  const float* const pA = p.ws + OFF_PA2;
  const float* const wihc = p.ws + OFF_WIHC;
  const float* hold = p.ws + ((step & 1) ? OFF_H1 : OFF_H0) + (size_t)row * HID_;
  float* hnew = p.ws + ((step & 1) ? OFF_H0 : OFF_H1) + (size_t)row * HID_;
  us_t* hhi = (us_t*)(p.ws + OFF_HHI) + (size_t)row * HID_;
  const float cd = (step > 0) ? (p.ws + OFF_CNTD)[row] : 0.f;
  float incd = 0.f, termd = 0.f;
  #pragma unroll
  for (int q = 0; q < 4; ++q) {
    const int c = tid + q * NT_;
    float gr_ = gi[c], gz_ = gi[1024 + c], gn_ = gi[2048 + c];
    float hr_ = 0.f, hz_ = 0.f, hn_ = 0.f, hv = 0.f;
    if (step > 0) {
      #pragma unroll
      for (int t6 = 0; t6 < 6; ++t6) {
        const float* pp = pA + (size_t)t6 * 786432 + base;
        gr_ += pp[c]; gz_ += pp[1024 + c]; gn_ += pp[2048 + c];
      }
      gr_ += cd * wihc[c];
      gz_ += cd * wihc[1024 + c];
      gn_ += cd * wihc[2048 + c];
      gi[c] = gr_; gi[1024 + c] = gz_; gi[2048 + c] = gn_;   // materialize for tail
      hr_ = gh[c]; hz_ = gh[1024 + c]; hn_ = gh[2048 + c];
      hv = hold[c];
    }
    float rr = sigm(gr_ + p.bih[c] + hr_ + p.bhh[c]);
    float zz = sigm(gz_ + p.bih[1024 + c] + hz_ + p.bhh[1024 + c]);
    float nn = tanh_(gn_ + p.bih[2048 + c] + rr * (hn_ + p.bhh[2048 + c]));
    float h2 = (1.f - zz) * nn + zz * hv;
    hnew[c] = h2;
    hhi[c] = f2bf(h2);
    incd = fmaf(h2, p.incw[c], incd);
    termd = fmaf(h2, p.termw[c], termd);
  }
  #pragma unroll
  for (int off = 32; off > 0; off >>= 1) {
    incd += __shfl_down(incd, off);
    termd += __shfl_down(termd, off);
  }
  if ((tid & 63) == 0) { sred[tid >> 6] = incd; sred[4 + (tid >> 6)] = termd; }
  __syncthreads();
  if (tid == 0) {
    float it = sred[0] + sred[1] + sred[2] + sred[3];
    float tt = sred[4] + sred[5] + sred[6] + sred[7];
    float cdn = sigm(it + p.incb[0]);
    (p.ws + OFF_CNTD)[row] = cdn;
    if (step == 0) p.out[row] = cdn;     // step0 writes (d_out not pre-zeroed)
    else p.out[row] += cdn;
    if (tt + p.termb[0] <= 0.f) atomicAnd(&flags[step], 0);
  }
}

// ---- stepW: blocks [0,256) write-GEMM split-K=8 (ww f32 stage-cvt);
//      blocks [256,352) G2: gh = h @ whh(f32)^T for step+1 ----
__global__ __launch_bounds__(NT_) void stepW_mfma(Params p, int step) {
  __shared__ us_t sm[12288];
  int* flags = (int*)(p.ws + OFF_FLAGS);
  const int b = blockIdx.x;
  if (b < 256) {
    if (step > 0 && ((volatile int*)flags)[step - 1]) return;
    const int ks = b & 7, t = b >> 3;
    const int mt = t >> 3, nt = t & 7;
    const us_t* A = (us_t*)(p.ws + OFF_HHI) + (size_t)mt * 64 * HID_ + ks * 128;
    const float* B = p.ww + (size_t)nt * 128 * HID_ + ks * 128;
    float* dst = p.ws + OFF_PW + ks * (B_ * HW_) + (size_t)mt * 64 * HW_ + nt * 128;
    mfma_block(A, HID_, B, HID_, 2, sm, sm + 4096, dst, HW_);
  } else {
    if (((volatile int*)flags)[step]) return;   // step+1 won't run
    const int r = b - 256;                      // 96 = 4mt x 24nt
    const int mt = r / 24, nt = r - mt * 24;
    const us_t* A = (us_t*)(p.ws + OFF_HHI) + (size_t)mt * 64 * HID_;
    const float* B = p.whh + (size_t)nt * 128 * HID_;
    float* dst = p.ws + OFF_GH + (size_t)mt * 64 * H3_ + nt * 128;
    mfma_block(A, HID_, B, HID_, 16, sm, sm + 4096, dst, H3_);
  }
}

// ------- stepWepi: reduce partials, sigmoid, mask write/accum, wsig/wsig2 emit -------
__global__ __launch_bounds__(NT_) void stepWepi_kernel(Params p, int step) {
  if (step > 0 && ((volatile int*)(p.ws + OFF_FLAGS))[step - 1]) return;
  const int i = (blockIdx.x * NT_ + threadIdx.x) * 4;   // 256 blocks exact
  const int m = i >> 10, n = i & 1023;
  const float* pW = p.ws + OFF_PW;
  float4 s = *(const float4*)(p.wb + n);
  #pragma unroll
  for (int ks = 0; ks < 8; ++ks) {
    float4 v = *(const float4*)(pW + ks * (B_ * HW_) + i);
    s.x += v.x; s.y += v.y; s.z += v.z; s.w += v.w;
  }
  float4 sv = {sigm(s.x), sigm(s.y), sigm(s.z), sigm(s.w)};
  float* op = p.out + B_ + i;
  if (step == 0) {
    *(float4*)op = sv;                 // step0 writes (d_out not pre-zeroed)
  } else {
    float4 ov = *(float4*)op;
    ov.x += sv.x; ov.y += sv.y; ov.z += sv.z; ov.w += sv.w;
    *(float4*)op = ov;
  }
  *(float4*)(p.ws + OFF_WSIG + i) = sv;
  us_t* w2 = (us_t*)(p.ws + OFF_WSIG2) + (size_t)m * 2048 + n;
  us_t h0 = f2bf(sv.x), h1 = f2bf(sv.y), h2b = f2bf(sv.z), h3 = f2bf(sv.w);
  *(uint2*)w2 = make_uint2((u32)h0 | ((u32)h1 << 16), (u32)h2b | ((u32)h3 << 16));
  *(uint2*)(w2 + 1024) = make_uint2(
      pack2(sv.x - bf2f(h0), sv.y - bf2f(h1)),
      pack2(sv.z - bf2f(h2b), sv.w - bf2f(h3)));
}

// ---------------- tail-only fused B phase (f32, self-contained) ----------------
DEVI void b_job(const Params& p, float* sh2, float* swb,
                const float* gi, const float* gh, const float* hold,
                float* hnew, float* wsig, float* cntd, int* dflag, int job) {
  const int tid = threadIdx.x;
  const int mt = job >> 3, nt = job & 7;
  const int r0 = mt * 8, c0 = nt * 128;
  const int gr = tid >> 5;
  const int gk = (tid & 31) * 2;
  const int wr = tid & 7;
  const int wc = (tid >> 3) * 4;
  const int row = r0 + gr;
  const float* giR = gi + row * H3_;
  const float* ghR = gh + row * H3_;
  const float* hR = hold + row * HID_;
  float* hW = hnew + row * HID_;
  float acc[4] = {0.f, 0.f, 0.f, 0.f};
  float incd = 0.f, termd = 0.f;
  const bool wh = (nt == 0);
  for (int kc = 0; kc < HID_; kc += 64) {
    float2 gxr = ld2(giR + kc + gk);
    float2 gxz = ld2(giR + 1024 + kc + gk);
    float2 gxn = ld2(giR + 2048 + kc + gk);
    float2 ghr = ld2(ghR + kc + gk);
    float2 ghz = ld2(ghR + 1024 + kc + gk);
    float2 ghn = ld2(ghR + 2048 + kc + gk);
    float2 hol = ld2(hR + kc + gk);
    float2 bri = ld2(p.bih + kc + gk);
    float2 brh = ld2(p.bhh + kc + gk);
    float2 bzi = ld2(p.bih + 1024 + kc + gk);
    float2 bzh = ld2(p.bhh + 1024 + kc + gk);
    float2 bni = ld2(p.bih + 2048 + kc + gk);
    float2 bnh = ld2(p.bhh + 2048 + kc + gk);
    float2 iw = ld2(p.incw + kc + gk);
    float2 tw = ld2(p.termw + kc + gk);
    float h2[2];
    {
      float rr = sigm(gxr.x + bri.x + ghr.x + brh.x);
      float zz = sigm(gxz.x + bzi.x + ghz.x + bzh.x);
      float nn = tanh_(gxn.x + bni.x + rr * (ghn.x + bnh.x));
      h2[0] = (1.f - zz) * nn + zz * hol.x;
      rr = sigm(gxr.y + bri.y + ghr.y + brh.y);
      zz = sigm(gxz.y + bzi.y + ghz.y + bzh.y);
      nn = tanh_(gxn.y + bni.y + rr * (ghn.y + bnh.y));
      h2[1] = (1.f - zz) * nn + zz * hol.y;
    }
    incd = fmaf(h2[0], iw.x, fmaf(h2[1], iw.y, incd));
    termd = fmaf(h2[0], tw.x, fmaf(h2[1], tw.y, termd));
    float4 wreg[8];
    #pragma unroll
    for (int it = 0; it < 8; ++it) {
      int id = tid + it * 256;
      int c = id >> 4, k4 = (id & 15) * 4;
      wreg[it] = *(const float4*)(p.ww + (c0 + c) * HID_ + kc + k4);
    }
    __syncthreads();
    sh2[gr * 68 + gk] = h2[0];
    sh2[gr * 68 + gk + 1] = h2[1];
    #pragma unroll
    for (int it = 0; it < 8; ++it) {
      int id = tid + it * 256;
      int c = id >> 4, k4 = (id & 15) * 4;
      swb[(k4 + 0) * 132 + c] = wreg[it].x;
      swb[(k4 + 1) * 132 + c] = wreg[it].y;
      swb[(k4 + 2) * 132 + c] = wreg[it].z;
      swb[(k4 + 3) * 132 + c] = wreg[it].w;
    }
    if (wh) {
      *(float2*)(hW + kc + gk) = make_float2(h2[0], h2[1]);
      *(u32*)((us_t*)(p.ws + OFF_HHI) + row * HID_ + kc + gk) = pack2(h2[0], h2[1]);
    }
    __syncthreads();
    #pragma unroll 8
    for (int kk = 0; kk < 64; ++kk) {
      float a = sh2[wr * 68 + kk];
      float4 b = *(const float4*)(swb + kk * 132 + wc);
      acc[0] = fmaf(a, b.x, acc[0]);
      acc[1] = fmaf(a, b.y, acc[1]);
      acc[2] = fmaf(a, b.z, acc[2]);
      acc[3] = fmaf(a, b.w, acc[3]);
    }
  }
  if (wh) {
    #pragma unroll
    for (int off = 16; off > 0; off >>= 1) {
      incd += __shfl_down(incd, off, 32);
      termd += __shfl_down(termd, off, 32);
    }
    if ((tid & 31) == 0) {
      float cd = sigm(incd + p.incb[0]);
      cntd[row] = cd;
      p.out[row] += cd;
      if (termd + p.termb[0] <= 0.f) atomicAnd(dflag, 0);
    }
  }
  {
    const int m = r0 + wr;
    float4 wb4 = *(const float4*)(p.wb + c0 + wc);
    float4 sv = {sigm(acc[0] + wb4.x), sigm(acc[1] + wb4.y),
                 sigm(acc[2] + wb4.z), sigm(acc[3] + wb4.w)};
    float* op = p.out + B_ + m * HW_ + c0 + wc;
    float4 ov = *(float4*)op;
    ov.x += sv.x; ov.y += sv.y; ov.z += sv.z; ov.w += sv.w;
    *(float4*)op = ov;
    *(float4*)(wsig + m * HID_ + c0 + wc) = sv;
    us_t* w2 = (us_t*)(p.ws + OFF_WSIG2) + m * 2048 + c0 + wc;
    us_t h0 = f2bf(sv.x), h1 = f2bf(sv.y), h2b = f2bf(sv.z), h3 = f2bf(sv.w);
    *(uint2*)w2 = make_uint2((u32)h0 | ((u32)h1 << 16), (u32)h2b | ((u32)h3 << 16));
    *(uint2*)(w2 + 1024) = make_uint2(
        pack2(sv.x - bf2f(h0), sv.y - bf2f(h1)),
        pack2(sv.z - bf2f(h2b), sv.w - bf2f(h3)));
  }
}

// ---- f32 double-buffered 64x64 GEMM tile (tail fallback); SB = scalar B loads ----
template <bool SB>
DEVI void gemm_db64(const float* __restrict__ A, int lda,
                    const float* __restrict__ Bw, int ldb, int K,
                    float* __restrict__ As, float* __restrict__ Bs,
                    float (&acc)[4][4]) {
  constexpr int P = 68;
  const int tid = threadIdx.x;
  const int tx = tid & 15, ty = tid >> 4;
  const int lr = tid >> 2, lk = (tid & 3) << 2;
  #pragma unroll
  for (int i = 0; i < 4; ++i)
    #pragma unroll
    for (int j = 0; j < 4; ++j) acc[i][j] = 0.f;
  auto ldb4 = [&](int k0) {
    float4 v;
    if constexpr (SB) {
      const float* q = Bw + (size_t)lr * ldb + k0 + lk;
      v.x = q[0]; v.y = q[1]; v.z = q[2]; v.w = q[3];
    } else {
      v = *(const float4*)(Bw + (size_t)lr * ldb + k0 + lk);
    }
    return v;
  };
  float4 va = *(const float4*)(A + lr * lda + lk);
  float4 vb = ldb4(0);
  As[(lk + 0) * P + lr] = va.x; As[(lk + 1) * P + lr] = va.y;
  As[(lk + 2) * P + lr] = va.z; As[(lk + 3) * P + lr] = va.w;
  Bs[(lk + 0) * P + lr] = vb.x; Bs[(lk + 1) * P + lr] = vb.y;
  Bs[(lk + 2) * P + lr] = vb.z; Bs[(lk + 3) * P + lr] = vb.w;
  __syncthreads();
  int cur = 0;
  for (int k0 = 16; k0 < K; k0 += 16) {
    va = *(const float4*)(A + lr * lda + k0 + lk);
    vb = ldb4(k0);
    const float* as = As + cur * (16 * P);
    const float* bs = Bs + cur * (16 * P);
    #pragma unroll
    for (int kk = 0; kk < 16; ++kk) {
      float a[4], b[4];
      ld4(a, as + kk * P + ty * 4);
      ld4(b, bs + kk * P + tx * 4);
      #pragma unroll
      for (int i = 0; i < 4; ++i)
        #pragma unroll
        for (int j = 0; j < 4; ++j) acc[i][j] = fmaf(a[i], b[j], acc[i][j]);
    }
    __syncthreads();
    float* asw = As + (cur ^ 1) * (16 * P);
    float* bsw = Bs + (cur ^ 1) * (16 * P);
    asw[(lk + 0) * P + lr] = va.x; asw[(lk + 1) * P + lr] = va.y;
    asw[(lk + 2) * P + lr] = va.z; asw[(lk + 3) * P + lr] = va.w;
    bsw[(lk + 0) * P + lr] = vb.x; bsw[(lk + 1) * P + lr] = vb.y;
    bsw[(lk + 2) * P + lr] = vb.z; bsw[(lk + 3) * P + lr] = vb.w;
    __syncthreads();
    cur ^= 1;
  }
  const float* as = As + cur * (16 * P);
  const float* bs = Bs + cur * (16 * P);
  #pragma unroll
  for (int kk = 0; kk < 16; ++kk) {
    float a[4], b[4];
    ld4(a, as + kk * P + ty * 4);
    ld4(b, bs + kk * P + tx * 4);
    #pragma unroll
    for (int i = 0; i < 4; ++i)
      #pragma unroll
      for (int j = 0; j < 4; ++j) acc[i][j] = fmaf(a[i], b[j], acc[i][j]);
  }
}

// ---------------- cooperative tail (steps >= start; usually exits) ----------
__global__ __launch_bounds__(NT_, 2) void tail_kernel(Params p, int start) {
  int* flags = (int*)(p.ws + OFF_FLAGS);
  if (((volatile int*)flags)[start - 1]) return;
  cg::grid_group gg = cg::this_grid();
  __shared__ __align__(16) float smem[8992];
  float* As = smem;
  float* Bs = smem + 2176;
  float* sh2 = smem;
  float* swb = smem + 544;
  float* const ws = p.ws;
  float* const gi = ws + OFF_GI;
  float* const gh = ws + OFF_GH;
  float* const wsig = ws + OFF_WSIG;
  float* const cntd = ws + OFF_CNTD;
  const float* const wihc = ws + OFF_WIHC;
  const int tid = threadIdx.x;
  const int bid = blockIdx.x;
  const int nb = gridDim.x;
  const int tx = tid & 15, ty = tid >> 4;
  const int msteps = p.max_steps[0];

  for (int step = start; step < msteps; ++step) {
    float* hcur = ws + ((step & 1) ? OFF_H1 : OFF_H0);
    float* hnxt = ws + ((step & 1) ? OFF_H0 : OFF_H1);
    for (int job = bid; job < 384; job += nb) {
      float acc[4][4];
      if (job < 192) {
        const int mt = job / 48, nt = job - mt * 48;
        gemm_db64<true>(wsig + mt * 64 * HID_, HID_,
                        p.wih + (size_t)nt * 64 * XD_ + 512, XD_, HID_, As, Bs, acc);
        #pragma unroll
        for (int i = 0; i < 4; ++i) {
          const int m = mt * 64 + ty * 4 + i;
          const float cd = cntd[m];
          float4 wc4 = *(const float4*)(wihc + nt * 64 + tx * 4);
          float* gp = gi + m * H3_ + nt * 64 + tx * 4;
          float4 g = *(float4*)gp;
          g.x += acc[i][0] + cd * wc4.x;
          g.y += acc[i][1] + cd * wc4.y;
          g.z += acc[i][2] + cd * wc4.z;
          g.w += acc[i][3] + cd * wc4.w;
          *(float4*)gp = g;
        }
      } else {
        const int j = job - 192;
        const int mt = j / 48, nt = j - mt * 48;
        gemm_db64<false>(hcur + mt * 64 * HID_, HID_,
                         p.whh + (size_t)nt * 64 * HID_, HID_, HID_, As, Bs, acc);
        #pragma unroll
        for (int i = 0; i < 4; ++i) {
          float4 v = {acc[i][0], acc[i][1], acc[i][2], acc[i][3]};
          *(float4*)(gh + (mt * 64 + ty * 4 + i) * H3_ + nt * 64 + tx * 4) = v;
        }
      }
      __syncthreads();
    }
    gg.sync();
    for (int job = bid; job < 256; job += nb)
      b_job(p, sh2, swb, gi, gh, hcur, hnxt, wsig, cntd, &flags[step], job);
    gg.sync();
    if (((volatile int*)flags)[step]) break;
  }
}

extern "C" void kernel_launch(void* const* d_in, const int* in_sizes, int n_in,
                              void* d_out, int out_size, void* d_ws, size_t ws_size,
                              hipStream_t stream) {
  (void)in_sizes; (void)n_in; (void)out_size; (void)ws_size;
  Params prm;
  prm.grid = (const float*)d_in[0];
  prm.c1w  = (const float*)d_in[1];
  prm.c1b  = (const float*)d_in[2];
  prm.c2w  = (const float*)d_in[3];
  prm.c2b  = (const float*)d_in[4];
  prm.linw = (const float*)d_in[5];
  prm.linb = (const float*)d_in[6];
  prm.wih  = (const float*)d_in[7];
  prm.whh  = (const float*)d_in[8];
  prm.bih  = (const float*)d_in[9];
  prm.bhh  = (const float*)d_in[10];
  prm.ww   = (const float*)d_in[11];
  prm.wb   = (const float*)d_in[12];
  prm.incw = (const float*)d_in[13];
  prm.incb = (const float*)d_in[14];
  prm.termw = (const float*)d_in[15];
  prm.termb = (const float*)d_in[16];
  prm.max_steps = (const int*)d_in[17];
  prm.out = (float*)d_out;
  prm.ws = (float*)d_ws;

  hipLaunchKernelGGL(conv_kernel, dim3(512), dim3(NT_), 0, stream, prm);
  hipLaunchKernelGGL(lin_mfma, dim3(256), dim3(NT_), 0, stream, prm);    // needs conv only
  hipLaunchKernelGGL(prep_kernel, dim3(1024), dim3(NT_), 0, stream, prm);
  hipLaunchKernelGGL(red_kernel, dim3(512), dim3(NT_), 0, stream, prm);
  hipLaunchKernelGGL(a1_mfma, dim3(96), dim3(NT_), 0, stream, prm);

  // step 0 (G2 for step1 piggybacked on W0)
  hipLaunchKernelGGL(stepG_kernel, dim3(B_), dim3(NT_), 0, stream, prm, 0);
  hipLaunchKernelGGL(stepW_mfma, dim3(352), dim3(NT_), 0, stream, prm, 0);
  hipLaunchKernelGGL(stepWepi_kernel, dim3(256), dim3(NT_), 0, stream, prm, 0);
  // step 1 (G2 for step2 piggybacked on W1)
  hipLaunchKernelGGL(stepA_mfma, dim3(576), dim3(NT_), 0, stream, prm, 1);
  hipLaunchKernelGGL(stepG_kernel, dim3(B_), dim3(NT_), 0, stream, prm, 1);
  hipLaunchKernelGGL(stepW_mfma, dim3(352), dim3(NT_), 0, stream, prm, 1);
  hipLaunchKernelGGL(stepWepi_kernel, dim3(256), dim3(NT_), 0, stream, prm, 1);

  int start = 2;
  void* args[] = {(void*)&prm, (void*)&start};
  (void)hipLaunchCooperativeKernel((const void*)tail_kernel, dim3(384), dim3(NT_),
                                   args, 0, stream);
}

// Round 14
// 138.831 us; speedup vs baseline: 1.2828x; 1.2828x over previous
//
#include <hip/hip_runtime.h>
#include <hip/hip_cooperative_groups.h>

namespace cg = cooperative_groups;

#define DEVI static __device__ __forceinline__

typedef __attribute__((ext_vector_type(8))) short s8v;    // 8 bf16 (4 VGPR)
typedef __attribute__((ext_vector_type(4))) float f32x4;
typedef unsigned short us_t;
typedef unsigned int u32;

constexpr int NT_ = 256;
constexpr int B_ = 256, HW_ = 1024, IN_ = 512, HID_ = 1024, H3_ = 3072;
constexpr int XD_ = 1537;
constexpr int FLAT_ = 16384;

// ---- workspace layout (float offsets); ws_size = 256 MiB (R6 layout) ----
constexpr int OFF_WIHFBF = 0;                 // 3072*512 bf16
constexpr int OFF_WIHM2  = 393216;            // 3072*2048 bf16 (hi|lo)
constexpr int OFF_WHHBF  = 3538944;           // 3072*1024 bf16
constexpr int OFF_WIHC   = 5111808;           // 3072 f32
constexpr int OFF_CNTD   = 5114880;           // 256
constexpr int OFF_FLAGS  = 5115136;           // 128 ints
constexpr int OFF_FEATBF = 5115264;           // 256*512 bf16
constexpr int OFF_GI     = 5180800;           // 786432 f32
constexpr int OFF_GH     = 5967232;           // 786432
constexpr int OFF_H0     = 6753664;           // 262144
constexpr int OFF_H1     = 7015808;           // 262144
constexpr int OFF_WSIG   = 7277952;           // 262144 f32 (tail path)
constexpr int OFF_HHI    = 7540096;           // 256*1024 bf16
constexpr int OFF_WSIG2  = 7671168;           // 256*2048 bf16 (hi|lo)
constexpr int OFF_C2BF   = 7933312;           // 256*16384 bf16 (dead after lin)
constexpr int OFF_LINWBF = 10030464;          // 512*16384 bf16 (dead after lin)
// aliases / extras:
constexpr int OFF_PART = OFF_GI;              // lin split-K partials (16*131072)
constexpr int OFF_PW   = OFF_C2BF;            // stepW partials 8*262144 (dead c2bf)
constexpr int OFF_WWBF = 10292608;            // 1024*1024 bf16 (inside dead linwbf)
constexpr int OFF_PA2  = 14224768;            // stepA partials 8*786432 f32

struct Params {
  const float* grid;
  const float* c1w; const float* c1b;
  const float* c2w; const float* c2b;
  const float* linw; const float* linb;
  const float* wih; const float* whh;
  const float* bih; const float* bhh;
  const float* ww;  const float* wb;
  const float* incw; const float* incb;
  const float* termw; const float* termb;
  const int* max_steps;
  float* out;   // [0:256) count, [256:262400) mask [256][1024]
  float* ws;
};

DEVI float sigm(float x) { return 1.f / (1.f + __expf(-x)); }
DEVI float tanh_(float x) { return 1.f - 2.f / (__expf(2.f * x) + 1.f); }
DEVI float2 ld2(const float* p) { return *(const float2*)p; }
DEVI void ld4(float* d, const float* p) {
  float4 v = *(const float4*)p; d[0] = v.x; d[1] = v.y; d[2] = v.z; d[3] = v.w;
}
DEVI us_t f2bf(float x) {            // RNE f32->bf16
  union { float f; u32 u; } v; v.f = x;
  u32 r = v.u + 0x7FFFu + ((v.u >> 16) & 1u);
  return (us_t)(r >> 16);
}
DEVI float bf2f(us_t h) {
  union { u32 u; float f; } v; v.u = ((u32)h) << 16; return v.f;
}
DEVI u32 pack2(float a, float b) { return (u32)f2bf(a) | ((u32)f2bf(b) << 16); }

// ------- front: blocks [0,256) conv; blocks [256,2304) prep conversions -------
__global__ __launch_bounds__(NT_) void front_kernel(Params p) {
  __shared__ float smem[34 * 34 + 8 * 34 * 34];
  const int tid = threadIdx.x;
  if (blockIdx.x < 256) {
    float* s_in = smem;
    float* s_c1 = smem + 34 * 34;
    const int b = blockIdx.x;
    for (int i = tid; i < 34 * 34; i += NT_) s_in[i] = 0.f;
    for (int i = tid; i < 8 * 34 * 34; i += NT_) s_c1[i] = 0.f;
    __syncthreads();
    for (int i = tid; i < 1024; i += NT_) {
      int y = i >> 5, x = i & 31;
      s_in[(y + 1) * 34 + (x + 1)] = p.grid[b * 1024 + i];
    }
    __syncthreads();
    const int pos0 = tid * 4;
    const int y = pos0 >> 5, x0 = pos0 & 31;
    {
      float win[3][6];
      #pragma unroll
      for (int dy = 0; dy < 3; ++dy)
        #pragma unroll
        for (int c = 0; c < 6; ++c) win[dy][c] = s_in[(y + dy) * 34 + x0 + c];
      float acc[8][4];
      #pragma unroll
      for (int oc = 0; oc < 8; ++oc)
        #pragma unroll
        for (int i = 0; i < 4; ++i) acc[oc][i] = p.c1b[oc];
      #pragma unroll
      for (int oc = 0; oc < 8; ++oc)
        #pragma unroll
        for (int dy = 0; dy < 3; ++dy)
          #pragma unroll
          for (int dx = 0; dx < 3; ++dx) {
            float w = p.c1w[oc * 9 + dy * 3 + dx];
            #pragma unroll
            for (int i = 0; i < 4; ++i)
              acc[oc][i] = fmaf(w, win[dy][i + dx], acc[oc][i]);
          }
      #pragma unroll
      for (int oc = 0; oc < 8; ++oc)
        #pragma unroll
        for (int i = 0; i < 4; ++i)
          s_c1[oc * 1156 + (y + 1) * 34 + (x0 + i + 1)] = fmaxf(acc[oc][i], 0.f);
    }
    __syncthreads();
    {
      float acc[16][4];
      #pragma unroll
      for (int oc = 0; oc < 16; ++oc)
        #pragma unroll
        for (int i = 0; i < 4; ++i) acc[oc][i] = p.c2b[oc];
      for (int ic = 0; ic < 8; ++ic) {
        float win[3][6];
        #pragma unroll
        for (int dy = 0; dy < 3; ++dy)
          #pragma unroll
          for (int c = 0; c < 6; ++c)
            win[dy][c] = s_c1[ic * 1156 + (y + dy) * 34 + x0 + c];
        #pragma unroll
        for (int oc = 0; oc < 16; ++oc)
          #pragma unroll
          for (int dy = 0; dy < 3; ++dy)
            #pragma unroll
            for (int dx = 0; dx < 3; ++dx) {
              float w = p.c2w[oc * 72 + ic * 9 + dy * 3 + dx];
              #pragma unroll
              for (int i = 0; i < 4; ++i)
                acc[oc][i] = fmaf(w, win[dy][i + dx], acc[oc][i]);
            }
      }
      us_t* dst = (us_t*)(p.ws + OFF_C2BF) + b * FLAT_;
      #pragma unroll
      for (int oc = 0; oc < 16; ++oc) {
        u32 lo = pack2(fmaxf(acc[oc][0], 0.f), fmaxf(acc[oc][1], 0.f));
        u32 hi = pack2(fmaxf(acc[oc][2], 0.f), fmaxf(acc[oc][3], 0.f));
        *(uint2*)(dst + oc * 1024 + pos0) = make_uint2(lo, hi);
      }
    }
  } else {
    const int gt = (blockIdx.x - 256) * NT_ + tid;
    const int gs = 2048 * NT_;
    us_t* wihf = (us_t*)(p.ws + OFF_WIHFBF);
    us_t* wihm2 = (us_t*)(p.ws + OFF_WIHM2);
    us_t* whhbf = (us_t*)(p.ws + OFF_WHHBF);
    us_t* linwbf = (us_t*)(p.ws + OFF_LINWBF);
    float* wihc = p.ws + OFF_WIHC;
    int* flags = (int*)(p.ws + OFF_FLAGS);
    for (int i = gt; i < (IN_ * FLAT_) / 4; i += gs) {
      float4 v = *(const float4*)(p.linw + (size_t)i * 4);
      *(uint2*)(linwbf + (size_t)i * 4) = make_uint2(pack2(v.x, v.y), pack2(v.z, v.w));
    }
    for (int i = gt; i < (H3_ * HID_) / 4; i += gs) {
      float4 v = *(const float4*)(p.whh + (size_t)i * 4);
      *(uint2*)(whhbf + (size_t)i * 4) = make_uint2(pack2(v.x, v.y), pack2(v.z, v.w));
    }
    for (int i = gt; i < H3_ * IN_; i += gs) {
      int n = i >> 9, k = i & 511;
      wihf[i] = f2bf(p.wih[n * XD_ + k]);
    }
    for (int i = gt; i < H3_ * HID_; i += gs) {
      int n = i >> 10, k = i & 1023;
      float v = p.wih[n * XD_ + 512 + k];
      us_t hi = f2bf(v);
      wihm2[n * 2048 + k] = hi;
      wihm2[n * 2048 + 1024 + k] = f2bf(v - bf2f(hi));
    }
    for (int i = gt; i < H3_; i += gs) wihc[i] = p.wih[i * XD_ + 1536];
    for (int i = gt; i < 128; i += gs) flags[i] = 1;
  }
}

// ---- MFMA block: C[64][128] = sum_k A[m][k]*B[n][k], bf16 in, f32 out ----
// 256 threads = 4 waves; wave w owns 64x32; K = nc*64.
// LDS swizzle: 16B unit (r,u) -> slot r*8 + (u ^ (r&7)).
DEVI void mfma_block(const us_t* __restrict__ Ag, int lda,
                     const us_t* __restrict__ Bg, int ldb, int nc,
                     us_t* __restrict__ sA, us_t* __restrict__ sB,
                     float* __restrict__ dst, int ldd) {
  const int tid = threadIdx.x;
  const int ar = tid >> 3, au = tid & 7;
  const int sw = au ^ (ar & 7);
  const int abase = (ar * 8 + sw) * 8;
  const us_t* a0p = Ag + (size_t)ar * lda + au * 8;
  const us_t* a1p = Ag + (size_t)(ar + 32) * lda + au * 8;
  const us_t* b0p = Bg + (size_t)ar * ldb + au * 8;
  const us_t* b1p = b0p + (size_t)32 * ldb;
  const us_t* b2p = b0p + (size_t)64 * ldb;
  const us_t* b3p = b0p + (size_t)96 * ldb;
  f32x4 acc[4][2];
  #pragma unroll
  for (int f = 0; f < 4; ++f) { acc[f][0] = (f32x4)0.f; acc[f][1] = (f32x4)0.f; }
  s8v ra0 = *(const s8v*)a0p;
  s8v ra1 = *(const s8v*)a1p;
  s8v rb0 = *(const s8v*)b0p;
  s8v rb1 = *(const s8v*)b1p;
  s8v rb2 = *(const s8v*)b2p;
  s8v rb3 = *(const s8v*)b3p;
  const int w = tid >> 6;
  const int lane = tid & 63;
  const int l15 = lane & 15, l4 = lane >> 4;
  const int rsw = l15 & 7;
  int c = 0;
  for (;;) {
    __syncthreads();
    *(s8v*)(sA + abase) = ra0;
    *(s8v*)(sA + abase + 2048) = ra1;
    *(s8v*)(sB + abase) = rb0;
    *(s8v*)(sB + abase + 2048) = rb1;
    *(s8v*)(sB + abase + 4096) = rb2;
    *(s8v*)(sB + abase + 6144) = rb3;
    ++c;
    if (c < nc) {
      const int ko = c * 64;
      ra0 = *(const s8v*)(a0p + ko);
      ra1 = *(const s8v*)(a1p + ko);
      rb0 = *(const s8v*)(b0p + ko);
      rb1 = *(const s8v*)(b1p + ko);
      rb2 = *(const s8v*)(b2p + ko);
      rb3 = *(const s8v*)(b3p + ko);
    }
    __syncthreads();
    #pragma unroll
    for (int kk = 0; kk < 2; ++kk) {
      const int uoff = ((kk * 4 + l4) ^ rsw) * 8;
      s8v bA = *(const s8v*)(sB + (w * 32 + l15) * 64 + uoff);
      s8v bB = *(const s8v*)(sB + (w * 32 + 16 + l15) * 64 + uoff);
      #pragma unroll
      for (int f = 0; f < 4; ++f) {
        s8v a = *(const s8v*)(sA + (f * 16 + l15) * 64 + uoff);
        acc[f][0] = __builtin_amdgcn_mfma_f32_16x16x32_bf16(a, bA, acc[f][0], 0, 0, 0);
        acc[f][1] = __builtin_amdgcn_mfma_f32_16x16x32_bf16(a, bB, acc[f][1], 0, 0, 0);
      }
    }
    if (c >= nc) break;
  }
  #pragma unroll
  for (int f = 0; f < 4; ++f)
    #pragma unroll
    for (int g = 0; g < 2; ++g) {
      float* dp = dst + (size_t)(f * 16 + l4 * 4) * ldd + w * 32 + g * 16 + l15;
      #pragma unroll
      for (int j = 0; j < 4; ++j) dp[(size_t)j * ldd] = acc[f][g][j];
    }
}

// ---------------- linear: part[ks] = c2f_bf @ linw_bf^T ----------------
__global__ __launch_bounds__(NT_) void lin_mfma(Params p) {
  __shared__ us_t sm[12288];
  const int b = blockIdx.x;                // 256 = 16ks x 4mt x 4nt
  const int ks = b & 15, t = b >> 4;
  const int mt = t >> 2, nt = t & 3;
  const us_t* A = (us_t*)(p.ws + OFF_C2BF) + (size_t)mt * 64 * FLAT_ + ks * 1024;
  const us_t* B = (us_t*)(p.ws + OFF_LINWBF) + (size_t)nt * 128 * FLAT_ + ks * 1024;
  float* dst = p.ws + OFF_PART + ks * (B_ * IN_) + mt * 64 * IN_ + nt * 128;
  mfma_block(A, FLAT_, B, FLAT_, 16, sm, sm + 4096, dst, IN_);
}

// ------------- reduce split-K -> feat bf16; also convert ww -> bf16 -------------
__global__ __launch_bounds__(NT_) void red_kernel(Params p) {
  const int gt = blockIdx.x * NT_ + threadIdx.x;   // 512 blocks, 131072 threads
  {
    const int o = gt & (IN_ - 1);
    const float* part = p.ws + OFF_PART;
    float s = p.linb[o];
    #pragma unroll
    for (int ks = 0; ks < 16; ++ks) s += part[ks * (B_ * IN_) + gt];
    ((us_t*)(p.ws + OFF_FEATBF))[gt] = f2bf(s);
  }
  us_t* wwbf = (us_t*)(p.ws + OFF_WWBF);
  #pragma unroll
  for (int r = 0; r < 2; ++r) {
    const int j = gt + r * 131072;                 // 262144 float4 units total
    float4 v = *(const float4*)(p.ww + (size_t)j * 4);
    *(uint2*)(wwbf + (size_t)j * 4) = make_uint2(pack2(v.x, v.y), pack2(v.z, v.w));
  }
}

// ---------------- gi_base = feat @ wihf^T ----------------
__global__ __launch_bounds__(NT_) void a1_mfma(Params p) {
  __shared__ us_t sm[12288];
  const int b = blockIdx.x;                // 96 = 4mt*24nt
  const int mt = b / 24, nt = b - mt * 24;
  const us_t* A = (us_t*)(p.ws + OFF_FEATBF) + (size_t)mt * 64 * IN_;
  const us_t* B = (us_t*)(p.ws + OFF_WIHFBF) + (size_t)nt * 128 * IN_;
  float* dst = p.ws + OFF_GI + (size_t)mt * 64 * H3_ + nt * 128;
  mfma_block(A, IN_, B, IN_, 8, sm, sm + 4096, dst, H3_);
}

// ------- A phase MFMA, split-K=2: 768 = 576 G1(3 terms x 2ks) + 192 G2(2ks) -------
__global__ __launch_bounds__(NT_) void stepA_mfma(Params p, int step) {
  if (((volatile int*)(p.ws + OFF_FLAGS))[step - 1]) return;
  __shared__ us_t sm[12288];
  const int b = blockIdx.x;
  if (b < 576) {
    const int term = b / 192;
    const int r = b - term * 192;
    const int ks = r / 96;
    const int t = r - ks * 96;
    const int mt = t / 24, nt = t - mt * 24;
    const us_t* A = (us_t*)(p.ws + OFF_WSIG2) + (size_t)mt * 64 * 2048 +
                    (term == 1 ? 1024 : 0) + ks * 512;
    const us_t* B = (us_t*)(p.ws + OFF_WIHM2) + (size_t)nt * 128 * 2048 +
                    (term == 2 ? 1024 : 0) + ks * 512;
    float* dst = p.ws + OFF_PA2 + (size_t)(term * 2 + ks) * 786432 +
                 (size_t)mt * 64 * H3_ + nt * 128;
    mfma_block(A, 2048, B, 2048, 8, sm, sm + 4096, dst, H3_);
  } else {
    const int r = b - 576;
    const int ks = r / 96;
    const int t = r - ks * 96;
    const int mt = t / 24, nt = t - mt * 24;
    const us_t* A = (us_t*)(p.ws + OFF_HHI) + (size_t)mt * 64 * HID_ + ks * 512;
    const us_t* B = (us_t*)(p.ws + OFF_WHHBF) + (size_t)nt * 128 * HID_ + ks * 512;
    float* dst = p.ws + OFF_PA2 + (size_t)(6 + ks) * 786432 +
                 (size_t)mt * 64 * H3_ + nt * 128;
    mfma_block(A, HID_, B, HID_, 8, sm, sm + 4096, dst, H3_);
  }
}

// ---- stepG: fold 8 A-partials into gi/gh, gates once per row, dots, count/flag ----
__global__ __launch_bounds__(NT_) void stepG_kernel(Params p, int step) {
  int* flags = (int*)(p.ws + OFF_FLAGS);
  if (step > 0 && ((volatile int*)flags)[step - 1]) return;
  __shared__ float sred[8];
  const int row = blockIdx.x;
  const int tid = threadIdx.x;
  const size_t base = (size_t)row * H3_;
  float* const gi = p.ws + OFF_GI + base;
  const float* const pA = p.ws + OFF_PA2;
  const float* const wihc = p.ws + OFF_WIHC;
  const float* hold = p.ws + ((step & 1) ? OFF_H1 : OFF_H0) + (size_t)row * HID_;
  float* hnew = p.ws + ((step & 1) ? OFF_H0 : OFF_H1) + (size_t)row * HID_;
  us_t* hhi = (us_t*)(p.ws + OFF_HHI) + (size_t)row * HID_;
  const float cd = (step > 0) ? (p.ws + OFF_CNTD)[row] : 0.f;
  float incd = 0.f, termd = 0.f;
  #pragma unroll
  for (int q = 0; q < 4; ++q) {
    const int c = tid + q * NT_;
    float gr_ = gi[c], gz_ = gi[1024 + c], gn_ = gi[2048 + c];
    float hr_ = 0.f, hz_ = 0.f, hn_ = 0.f, hv = 0.f;
    if (step > 0) {
      #pragma unroll
      for (int t6 = 0; t6 < 6; ++t6) {
        const float* pp = pA + (size_t)t6 * 786432 + base;
        gr_ += pp[c]; gz_ += pp[1024 + c]; gn_ += pp[2048 + c];
      }
      gr_ += cd * wihc[c];
      gz_ += cd * wihc[1024 + c];
      gn_ += cd * wihc[2048 + c];
      const float* q6 = pA + (size_t)6 * 786432 + base;
      const float* q7 = pA + (size_t)7 * 786432 + base;
      hr_ = q6[c] + q7[c];
      hz_ = q6[1024 + c] + q7[1024 + c];
      hn_ = q6[2048 + c] + q7[2048 + c];
      gi[c] = gr_; gi[1024 + c] = gz_; gi[2048 + c] = gn_;   // materialize for tail
      hv = hold[c];
    }
    float rr = sigm(gr_ + p.bih[c] + hr_ + p.bhh[c]);
    float zz = sigm(gz_ + p.bih[1024 + c] + hz_ + p.bhh[1024 + c]);
    float nn = tanh_(gn_ + p.bih[2048 + c] + rr * (hn_ + p.bhh[2048 + c]));
    float h2 = (1.f - zz) * nn + zz * hv;
    hnew[c] = h2;
    hhi[c] = f2bf(h2);
    incd = fmaf(h2, p.incw[c], incd);
    termd = fmaf(h2, p.termw[c], termd);
  }
  #pragma unroll
  for (int off = 32; off > 0; off >>= 1) {
    incd += __shfl_down(incd, off);
    termd += __shfl_down(termd, off);
  }
  if ((tid & 63) == 0) { sred[tid >> 6] = incd; sred[4 + (tid >> 6)] = termd; }
  __syncthreads();
  if (tid == 0) {
    float it = sred[0] + sred[1] + sred[2] + sred[3];
    float tt = sred[4] + sred[5] + sred[6] + sred[7];
    float cdn = sigm(it + p.incb[0]);
    (p.ws + OFF_CNTD)[row] = cdn;
    if (step == 0) p.out[row] = cdn;     // step0 writes (d_out not pre-zeroed)
    else p.out[row] += cdn;
    if (tt + p.termb[0] <= 0.f) atomicAnd(&flags[step], 0);
  }
}

// ---------------- stepW: write-GEMM partials via MFMA, split-K=8 ----------------
__global__ __launch_bounds__(NT_) void stepW_mfma(Params p, int step) {
  if (step > 0 && ((volatile int*)(p.ws + OFF_FLAGS))[step - 1]) return;
  __shared__ us_t sm[12288];
  const int b = blockIdx.x;           // 256 = 8ks x 4mt x 8nt
  const int ks = b & 7, t = b >> 3;
  const int mt = t >> 3, nt = t & 7;
  const us_t* A = (us_t*)(p.ws + OFF_HHI) + (size_t)mt * 64 * HID_ + ks * 128;
  const us_t* B = (us_t*)(p.ws + OFF_WWBF) + (size_t)nt * 128 * HID_ + ks * 128;
  float* dst = p.ws + OFF_PW + ks * (B_ * HW_) + (size_t)mt * 64 * HW_ + nt * 128;
  mfma_block(A, HID_, B, HID_, 2, sm, sm + 4096, dst, HW_);
}

// ------- stepWepi: reduce partials, sigmoid, mask write/accum, wsig/wsig2 emit -------
__global__ __launch_bounds__(NT_) void stepWepi_kernel(Params p, int step) {
  if (step > 0 && ((volatile int*)(p.ws + OFF_FLAGS))[step - 1]) return;
  const int i = (blockIdx.x * NT_ + threadIdx.x) * 4;   // 256 blocks exact
  const int m = i >> 10, n = i & 1023;
  const float* pW = p.ws + OFF_PW;
  float4 s = *(const float4*)(p.wb + n);
  #pragma unroll
  for (int ks = 0; ks < 8; ++ks) {
    float4 v = *(const float4*)(pW + ks * (B_ * HW_) + i);
    s.x += v.x; s.y += v.y; s.z += v.z; s.w += v.w;
  }
  float4 sv = {sigm(s.x), sigm(s.y), sigm(s.z), sigm(s.w)};
  float* op = p.out + B_ + i;
  if (step == 0) {
    *(float4*)op = sv;                 // step0 writes (d_out not pre-zeroed)
  } else {
    float4 ov = *(float4*)op;
    ov.x += sv.x; ov.y += sv.y; ov.z += sv.z; ov.w += sv.w;
    *(float4*)op = ov;
  }
  *(float4*)(p.ws + OFF_WSIG + i) = sv;
  us_t* w2 = (us_t*)(p.ws + OFF_WSIG2) + (size_t)m * 2048 + n;
  us_t h0 = f2bf(sv.x), h1 = f2bf(sv.y), h2b = f2bf(sv.z), h3 = f2bf(sv.w);
  *(uint2*)w2 = make_uint2((u32)h0 | ((u32)h1 << 16), (u32)h2b | ((u32)h3 << 16));
  *(uint2*)(w2 + 1024) = make_uint2(
      pack2(sv.x - bf2f(h0), sv.y - bf2f(h1)),
      pack2(sv.z - bf2f(h2b), sv.w - bf2f(h3)));
}

// ---------------- tail-only fused B phase (f32, self-contained) ----------------
DEVI void b_job(const Params& p, float* sh2, float* swb,
                const float* gi, const float* gh, const float* hold,
                float* hnew, float* wsig, float* cntd, int* dflag, int job) {
  const int tid = threadIdx.x;
  const int mt = job >> 3, nt = job & 7;
  const int r0 = mt * 8, c0 = nt * 128;
  const int gr = tid >> 5;
  const int gk = (tid & 31) * 2;
  const int wr = tid & 7;
  const int wc = (tid >> 3) * 4;
  const int row = r0 + gr;
  const float* giR = gi + row * H3_;
  const float* ghR = gh + row * H3_;
  const float* hR = hold + row * HID_;
  float* hW = hnew + row * HID_;
  float acc[4] = {0.f, 0.f, 0.f, 0.f};
  float incd = 0.f, termd = 0.f;
  const bool wh = (nt == 0);
  for (int kc = 0; kc < HID_; kc += 64) {
    float2 gxr = ld2(giR + kc + gk);
    float2 gxz = ld2(giR + 1024 + kc + gk);
    float2 gxn = ld2(giR + 2048 + kc + gk);
    float2 ghr = ld2(ghR + kc + gk);
    float2 ghz = ld2(ghR + 1024 + kc + gk);
    float2 ghn = ld2(ghR + 2048 + kc + gk);
    float2 hol = ld2(hR + kc + gk);
    float2 bri = ld2(p.bih + kc + gk);
    float2 brh = ld2(p.bhh + kc + gk);
    float2 bzi = ld2(p.bih + 1024 + kc + gk);
    float2 bzh = ld2(p.bhh + 1024 + kc + gk);
    float2 bni = ld2(p.bih + 2048 + kc + gk);
    float2 bnh = ld2(p.bhh + 2048 + kc + gk);
    float2 iw = ld2(p.incw + kc + gk);
    float2 tw = ld2(p.termw + kc + gk);
    float h2[2];
    {
      float rr = sigm(gxr.x + bri.x + ghr.x + brh.x);
      float zz = sigm(gxz.x + bzi.x + ghz.x + bzh.x);
      float nn = tanh_(gxn.x + bni.x + rr * (ghn.x + bnh.x));
      h2[0] = (1.f - zz) * nn + zz * hol.x;
      rr = sigm(gxr.y + bri.y + ghr.y + brh.y);
      zz = sigm(gxz.y + bzi.y + ghz.y + bzh.y);
      nn = tanh_(gxn.y + bni.y + rr * (ghn.y + bnh.y));
      h2[1] = (1.f - zz) * nn + zz * hol.y;
    }
    incd = fmaf(h2[0], iw.x, fmaf(h2[1], iw.y, incd));
    termd = fmaf(h2[0], tw.x, fmaf(h2[1], tw.y, termd));
    float4 wreg[8];
    #pragma unroll
    for (int it = 0; it < 8; ++it) {
      int id = tid + it * 256;
      int c = id >> 4, k4 = (id & 15) * 4;
      wreg[it] = *(const float4*)(p.ww + (c0 + c) * HID_ + kc + k4);
    }
    __syncthreads();
    sh2[gr * 68 + gk] = h2[0];
    sh2[gr * 68 + gk + 1] = h2[1];
    #pragma unroll
    for (int it = 0; it < 8; ++it) {
      int id = tid + it * 256;
      int c = id >> 4, k4 = (id & 15) * 4;
      swb[(k4 + 0) * 132 + c] = wreg[it].x;
      swb[(k4 + 1) * 132 + c] = wreg[it].y;
      swb[(k4 + 2) * 132 + c] = wreg[it].z;
      swb[(k4 + 3) * 132 + c] = wreg[it].w;
    }
    if (wh) {
      *(float2*)(hW + kc + gk) = make_float2(h2[0], h2[1]);
      *(u32*)((us_t*)(p.ws + OFF_HHI) + row * HID_ + kc + gk) = pack2(h2[0], h2[1]);
    }
    __syncthreads();
    #pragma unroll 8
    for (int kk = 0; kk < 64; ++kk) {
      float a = sh2[wr * 68 + kk];
      float4 b = *(const float4*)(swb + kk * 132 + wc);
      acc[0] = fmaf(a, b.x, acc[0]);
      acc[1] = fmaf(a, b.y, acc[1]);
      acc[2] = fmaf(a, b.z, acc[2]);
      acc[3] = fmaf(a, b.w, acc[3]);
    }
  }
  if (wh) {
    #pragma unroll
    for (int off = 16; off > 0; off >>= 1) {
      incd += __shfl_down(incd, off, 32);
      termd += __shfl_down(termd, off, 32);
    }
    if ((tid & 31) == 0) {
      float cd = sigm(incd + p.incb[0]);
      cntd[row] = cd;
      p.out[row] += cd;
      if (termd + p.termb[0] <= 0.f) atomicAnd(dflag, 0);
    }
  }
  {
    const int m = r0 + wr;
    float4 wb4 = *(const float4*)(p.wb + c0 + wc);
    float4 sv = {sigm(acc[0] + wb4.x), sigm(acc[1] + wb4.y),
                 sigm(acc[2] + wb4.z), sigm(acc[3] + wb4.w)};
    float* op = p.out + B_ + m * HW_ + c0 + wc;
    float4 ov = *(float4*)op;
    ov.x += sv.x; ov.y += sv.y; ov.z += sv.z; ov.w += sv.w;
    *(float4*)op = ov;
    *(float4*)(wsig + m * HID_ + c0 + wc) = sv;
    us_t* w2 = (us_t*)(p.ws + OFF_WSIG2) + m * 2048 + c0 + wc;
    us_t h0 = f2bf(sv.x), h1 = f2bf(sv.y), h2b = f2bf(sv.z), h3 = f2bf(sv.w);
    *(uint2*)w2 = make_uint2((u32)h0 | ((u32)h1 << 16), (u32)h2b | ((u32)h3 << 16));
    *(uint2*)(w2 + 1024) = make_uint2(
        pack2(sv.x - bf2f(h0), sv.y - bf2f(h1)),
        pack2(sv.z - bf2f(h2b), sv.w - bf2f(h3)));
  }
}

// ---- f32 double-buffered 64x64 GEMM tile (tail fallback); SB = scalar B loads ----
template <bool SB>
DEVI void gemm_db64(const float* __restrict__ A, int lda,
                    const float* __restrict__ Bw, int ldb, int K,
                    float* __restrict__ As, float* __restrict__ Bs,
                    float (&acc)[4][4]) {
  constexpr int P = 68;
  const int tid = threadIdx.x;
  const int tx = tid & 15, ty = tid >> 4;
  const int lr = tid >> 2, lk = (tid & 3) << 2;
  #pragma unroll
  for (int i = 0; i < 4; ++i)
    #pragma unroll
    for (int j = 0; j < 4; ++j) acc[i][j] = 0.f;
  auto ldb4 = [&](int k0) {
    float4 v;
    if constexpr (SB) {
      const float* q = Bw + (size_t)lr * ldb + k0 + lk;
      v.x = q[0]; v.y = q[1]; v.z = q[2]; v.w = q[3];
    } else {
      v = *(const float4*)(Bw + (size_t)lr * ldb + k0 + lk);
    }
    return v;
  };
  float4 va = *(const float4*)(A + lr * lda + lk);
  float4 vb = ldb4(0);
  As[(lk + 0) * P + lr] = va.x; As[(lk + 1) * P + lr] = va.y;
  As[(lk + 2) * P + lr] = va.z; As[(lk + 3) * P + lr] = va.w;
  Bs[(lk + 0) * P + lr] = vb.x; Bs[(lk + 1) * P + lr] = vb.y;
  Bs[(lk + 2) * P + lr] = vb.z; Bs[(lk + 3) * P + lr] = vb.w;
  __syncthreads();
  int cur = 0;
  for (int k0 = 16; k0 < K; k0 += 16) {
    va = *(const float4*)(A + lr * lda + k0 + lk);
    vb = ldb4(k0);
    const float* as = As + cur * (16 * P);
    const float* bs = Bs + cur * (16 * P);
    #pragma unroll
    for (int kk = 0; kk < 16; ++kk) {
      float a[4], b[4];
      ld4(a, as + kk * P + ty * 4);
      ld4(b, bs + kk * P + tx * 4);
      #pragma unroll
      for (int i = 0; i < 4; ++i)
        #pragma unroll
        for (int j = 0; j < 4; ++j) acc[i][j] = fmaf(a[i], b[j], acc[i][j]);
    }
    __syncthreads();
    float* asw = As + (cur ^ 1) * (16 * P);
    float* bsw = Bs + (cur ^ 1) * (16 * P);
    asw[(lk + 0) * P + lr] = va.x; asw[(lk + 1) * P + lr] = va.y;
    asw[(lk + 2) * P + lr] = va.z; asw[(lk + 3) * P + lr] = va.w;
    bsw[(lk + 0) * P + lr] = vb.x; bsw[(lk + 1) * P + lr] = vb.y;
    bsw[(lk + 2) * P + lr] = vb.z; bsw[(lk + 3) * P + lr] = vb.w;
    __syncthreads();
    cur ^= 1;
  }
  const float* as = As + cur * (16 * P);
  const float* bs = Bs + cur * (16 * P);
  #pragma unroll
  for (int kk = 0; kk < 16; ++kk) {
    float a[4], b[4];
    ld4(a, as + kk * P + ty * 4);
    ld4(b, bs + kk * P + tx * 4);
    #pragma unroll
    for (int i = 0; i < 4; ++i)
      #pragma unroll
      for (int j = 0; j < 4; ++j) acc[i][j] = fmaf(a[i], b[j], acc[i][j]);
  }
}

// ---------------- cooperative tail (steps >= start; usually exits) ----------
__global__ __launch_bounds__(NT_, 2) void tail_kernel(Params p, int start) {
  int* flags = (int*)(p.ws + OFF_FLAGS);
  if (((volatile int*)flags)[start - 1]) return;
  cg::grid_group gg = cg::this_grid();
  __shared__ __align__(16) float smem[8992];
  float* As = smem;
  float* Bs = smem + 2176;
  float* sh2 = smem;
  float* swb = smem + 544;
  float* const ws = p.ws;
  float* const gi = ws + OFF_GI;
  float* const gh = ws + OFF_GH;
  float* const wsig = ws + OFF_WSIG;
  float* const cntd = ws + OFF_CNTD;
  const float* const wihc = ws + OFF_WIHC;
  const int tid = threadIdx.x;
  const int bid = blockIdx.x;
  const int nb = gridDim.x;
  const int tx = tid & 15, ty = tid >> 4;
  const int msteps = p.max_steps[0];

  for (int step = start; step < msteps; ++step) {
    float* hcur = ws + ((step & 1) ? OFF_H1 : OFF_H0);
    float* hnxt = ws + ((step & 1) ? OFF_H0 : OFF_H1);
    for (int job = bid; job < 384; job += nb) {
      float acc[4][4];
      if (job < 192) {
        const int mt = job / 48, nt = job - mt * 48;
        gemm_db64<true>(wsig + mt * 64 * HID_, HID_,
                        p.wih + (size_t)nt * 64 * XD_ + 512, XD_, HID_, As, Bs, acc);
        #pragma unroll
        for (int i = 0; i < 4; ++i) {
          const int m = mt * 64 + ty * 4 + i;
          const float cd = cntd[m];
          float4 wc4 = *(const float4*)(wihc + nt * 64 + tx * 4);
          float* gp = gi + m * H3_ + nt * 64 + tx * 4;
          float4 g = *(float4*)gp;
          g.x += acc[i][0] + cd * wc4.x;
          g.y += acc[i][1] + cd * wc4.y;
          g.z += acc[i][2] + cd * wc4.z;
          g.w += acc[i][3] + cd * wc4.w;
          *(float4*)gp = g;
        }
      } else {
        const int j = job - 192;
        const int mt = j / 48, nt = j - mt * 48;
        gemm_db64<false>(hcur + mt * 64 * HID_, HID_,
                         p.whh + (size_t)nt * 64 * HID_, HID_, HID_, As, Bs, acc);
        #pragma unroll
        for (int i = 0; i < 4; ++i) {
          float4 v = {acc[i][0], acc[i][1], acc[i][2], acc[i][3]};
          *(float4*)(gh + (mt * 64 + ty * 4 + i) * H3_ + nt * 64 + tx * 4) = v;
        }
      }
      __syncthreads();
    }
    gg.sync();
    for (int job = bid; job < 256; job += nb)
      b_job(p, sh2, swb, gi, gh, hcur, hnxt, wsig, cntd, &flags[step], job);
    gg.sync();
    if (((volatile int*)flags)[step]) break;
  }
}

extern "C" void kernel_launch(void* const* d_in, const int* in_sizes, int n_in,
                              void* d_out, int out_size, void* d_ws, size_t ws_size,
                              hipStream_t stream) {
  (void)in_sizes; (void)n_in; (void)out_size; (void)ws_size;
  Params prm;
  prm.grid = (const float*)d_in[0];
  prm.c1w  = (const float*)d_in[1];
  prm.c1b  = (const float*)d_in[2];
  prm.c2w  = (const float*)d_in[3];
  prm.c2b  = (const float*)d_in[4];
  prm.linw = (const float*)d_in[5];
  prm.linb = (const float*)d_in[6];
  prm.wih  = (const float*)d_in[7];
  prm.whh  = (const float*)d_in[8];
  prm.bih  = (const float*)d_in[9];
  prm.bhh  = (const float*)d_in[10];
  prm.ww   = (const float*)d_in[11];
  prm.wb   = (const float*)d_in[12];
  prm.incw = (const float*)d_in[13];
  prm.incb = (const float*)d_in[14];
  prm.termw = (const float*)d_in[15];
  prm.termb = (const float*)d_in[16];
  prm.max_steps = (const int*)d_in[17];
  prm.out = (float*)d_out;
  prm.ws = (float*)d_ws;

  hipLaunchKernelGGL(front_kernel, dim3(2304), dim3(NT_), 0, stream, prm);
  hipLaunchKernelGGL(lin_mfma, dim3(256), dim3(NT_), 0, stream, prm);
  hipLaunchKernelGGL(red_kernel, dim3(512), dim3(NT_), 0, stream, prm);
  hipLaunchKernelGGL(a1_mfma, dim3(96), dim3(NT_), 0, stream, prm);

  constexpr int U = 2;   // unrolled steps; data terminates at step 1
  hipLaunchKernelGGL(stepG_kernel, dim3(B_), dim3(NT_), 0, stream, prm, 0);
  hipLaunchKernelGGL(stepW_mfma, dim3(256), dim3(NT_), 0, stream, prm, 0);
  hipLaunchKernelGGL(stepWepi_kernel, dim3(256), dim3(NT_), 0, stream, prm, 0);
  for (int t = 1; t < U; ++t) {
    hipLaunchKernelGGL(stepA_mfma, dim3(768), dim3(NT_), 0, stream, prm, t);
    hipLaunchKernelGGL(stepG_kernel, dim3(B_), dim3(NT_), 0, stream, prm, t);
    hipLaunchKernelGGL(stepW_mfma, dim3(256), dim3(NT_), 0, stream, prm, t);
    hipLaunchKernelGGL(stepWepi_kernel, dim3(256), dim3(NT_), 0, stream, prm, t);
  }
  int start = U;
  void* args[] = {(void*)&prm, (void*)&start};
  (void)hipLaunchCooperativeKernel((const void*)tail_kernel, dim3(384), dim3(NT_),
                                   args, 0, stream);
}